// Round 1
// baseline (157.411 us; speedup 1.0000x reference)
//
#include <hip/hip_runtime.h>

// Kernel 1: single-thread precompute.
// Builds the fixed post-encoding circuit unitary U (8x8 complex), then
// M = Re(U^dag Z0 U) (8x8 real symmetric), then contracts M down to the
// 27 trilinear coefficients B[a][b][g] such that
//   z = sum_{a,b,g} B[a][b][g] * g0_a * g1_b * g2_g,
// where gi = (1, cos x_i, sin x_i).
__global__ void vqc_coeffs_kernel(const float* __restrict__ w, float* __restrict__ Bout) {
    if (threadIdx.x != 0 || blockIdx.x != 0) return;

    float Ur[8][8], Ui[8][8];   // U[i][j]: amplitude i of column j
#pragma unroll
    for (int i = 0; i < 8; ++i)
#pragma unroll
        for (int j = 0; j < 8; ++j) { Ur[i][j] = (i == j) ? 1.f : 0.f; Ui[i][j] = 0.f; }

#pragma unroll
    for (int l = 0; l < 3; ++l) {
#pragma unroll
        for (int q = 0; q < 3; ++q) {
            const int m = 4 >> q;   // qubit q bit in flat index (q0*4 + q1*2 + q2)
            // RY(w[l][q][0])
            {
                float th = 0.5f * w[(l * 3 + q) * 2 + 0];
                float c = cosf(th), s = sinf(th);
#pragma unroll
                for (int i = 0; i < 8; ++i) {
                    if (i & m) continue;
                    const int i1 = i | m;
#pragma unroll
                    for (int j = 0; j < 8; ++j) {
                        float a0r = Ur[i][j],  a0i = Ui[i][j];
                        float a1r = Ur[i1][j], a1i = Ui[i1][j];
                        Ur[i][j]  = c * a0r - s * a1r;  Ui[i][j]  = c * a0i - s * a1i;
                        Ur[i1][j] = s * a0r + c * a1r;  Ui[i1][j] = s * a0i + c * a1i;
                    }
                }
            }
            // RZ(w[l][q][1]) = diag(e^{-i t/2}, e^{+i t/2}) on qubit q
            {
                float ph = 0.5f * w[(l * 3 + q) * 2 + 1];
                float cz = cosf(ph), sz = sinf(ph);
#pragma unroll
                for (int i = 0; i < 8; ++i) {
                    float er = cz, ei = (i & m) ? sz : -sz;
#pragma unroll
                    for (int j = 0; j < 8; ++j) {
                        float ar = Ur[i][j], ai = Ui[i][j];
                        Ur[i][j] = er * ar - ei * ai;
                        Ui[i][j] = er * ai + ei * ar;
                    }
                }
            }
        }
        // CNOT01 (control q0, target q1): rows 4<->6, 5<->7
#pragma unroll
        for (int j = 0; j < 8; ++j) {
            float t;
            t = Ur[4][j]; Ur[4][j] = Ur[6][j]; Ur[6][j] = t;
            t = Ui[4][j]; Ui[4][j] = Ui[6][j]; Ui[6][j] = t;
            t = Ur[5][j]; Ur[5][j] = Ur[7][j]; Ur[7][j] = t;
            t = Ui[5][j]; Ui[5][j] = Ui[7][j]; Ui[7][j] = t;
        }
        // CNOT12 (control q1, target q2): rows 2<->3, 6<->7
#pragma unroll
        for (int j = 0; j < 8; ++j) {
            float t;
            t = Ur[2][j]; Ur[2][j] = Ur[3][j]; Ur[3][j] = t;
            t = Ui[2][j]; Ui[2][j] = Ui[3][j]; Ui[3][j] = t;
            t = Ur[6][j]; Ur[6][j] = Ur[7][j]; Ur[7][j] = t;
            t = Ui[6][j]; Ui[6][j] = Ui[7][j]; Ui[7][j] = t;
        }
    }

    // M[j][k] = sum_i sign_i * Re(conj(U[i][j]) * U[i][k]); sign = +1 for i<4 (q0=0)
    float M[8][8];
#pragma unroll
    for (int j = 0; j < 8; ++j)
#pragma unroll
        for (int k = 0; k < 8; ++k) {
            float acc = 0.f;
#pragma unroll
            for (int i = 0; i < 8; ++i) {
                float t = Ur[i][j] * Ur[i][k] + Ui[i][j] * Ui[i][k];
                acc += (i < 4) ? t : -t;
            }
            M[j][k] = acc;
        }

    // Contract qubit-0 pair (u_a u_a') -> basis (1, cos x0, sin x0):
    //   c^2 = (1+cos)/2, s^2 = (1-cos)/2, cs = sin/2
    float T1[3][4][4];
#pragma unroll
    for (int jl = 0; jl < 4; ++jl)
#pragma unroll
        for (int kl = 0; kl < 4; ++kl) {
            T1[0][jl][kl] = 0.5f * (M[jl][kl] + M[4 + jl][4 + kl]);
            T1[1][jl][kl] = 0.5f * (M[jl][kl] - M[4 + jl][4 + kl]);
            T1[2][jl][kl] = 0.5f * (M[jl][4 + kl] + M[4 + jl][kl]);
        }
    // Contract qubit-1 pair
    float T2[3][3][2][2];
#pragma unroll
    for (int a = 0; a < 3; ++a)
#pragma unroll
        for (int c = 0; c < 2; ++c)
#pragma unroll
            for (int cp = 0; cp < 2; ++cp) {
                T2[a][0][c][cp] = 0.5f * (T1[a][c][cp] + T1[a][2 + c][2 + cp]);
                T2[a][1][c][cp] = 0.5f * (T1[a][c][cp] - T1[a][2 + c][2 + cp]);
                T2[a][2][c][cp] = 0.5f * (T1[a][c][2 + cp] + T1[a][2 + c][cp]);
            }
    // Contract qubit-2 pair -> 27 coefficients
#pragma unroll
    for (int a = 0; a < 3; ++a)
#pragma unroll
        for (int b = 0; b < 3; ++b) {
            Bout[(a * 3 + b) * 3 + 0] = 0.5f * (T2[a][b][0][0] + T2[a][b][1][1]);
            Bout[(a * 3 + b) * 3 + 1] = 0.5f * (T2[a][b][0][0] - T2[a][b][1][1]);
            Bout[(a * 3 + b) * 3 + 2] = 0.5f * (T2[a][b][0][1] + T2[a][b][1][0]);
        }
    Bout[27] = 0.f; // pad to 28 floats for float4 staging in kernel 2
}

// Kernel 2: per-sample evaluation. Memory-bound: one float4 read of the
// input row (cols 0..3; only 0..2 used), 3 fast sincos, 26 FMA, 1 store.
__global__ __launch_bounds__(256) void vqc_eval_kernel(
    const float* __restrict__ in, const float* __restrict__ coeffs,
    float* __restrict__ out, int B) {
    __shared__ float Bs[28];
    const int t = threadIdx.x;
    if (t < 7) reinterpret_cast<float4*>(Bs)[t] =
        reinterpret_cast<const float4*>(coeffs)[t];
    __syncthreads();

    const int b = blockIdx.x * 256 + t;
    if (b >= B) return;

    const float4 v = reinterpret_cast<const float4*>(in)[2 * b];
    float s0, c0, s1, c1, s2, c2;
    __sincosf(v.x, &s0, &c0);
    __sincosf(v.y, &s1, &c1);
    __sincosf(v.z, &s2, &c2);

    float e0 = 0.f, e1 = 0.f, e2 = 0.f;
#pragma unroll
    for (int a = 0; a < 3; ++a) {
        float h0 = Bs[(a * 3 + 0) * 3 + 0] + Bs[(a * 3 + 0) * 3 + 1] * c2 + Bs[(a * 3 + 0) * 3 + 2] * s2;
        float h1 = Bs[(a * 3 + 1) * 3 + 0] + Bs[(a * 3 + 1) * 3 + 1] * c2 + Bs[(a * 3 + 1) * 3 + 2] * s2;
        float h2 = Bs[(a * 3 + 2) * 3 + 0] + Bs[(a * 3 + 2) * 3 + 1] * c2 + Bs[(a * 3 + 2) * 3 + 2] * s2;
        float ea = h0 + h1 * c1 + h2 * s1;
        if (a == 0) e0 = ea; else if (a == 1) e1 = ea; else e2 = ea;
    }
    out[b] = e0 + e1 * c0 + e2 * s0;
}

extern "C" void kernel_launch(void* const* d_in, const int* in_sizes, int n_in,
                              void* d_out, int out_size, void* d_ws, size_t ws_size,
                              hipStream_t stream) {
    const float* inputs = (const float*)d_in[0];     // (B, 8) float32
    const float* qw     = (const float*)d_in[1];     // (3, 3, 2) float32
    float* out          = (float*)d_out;             // (B, 1) float32
    float* coeffs       = (float*)d_ws;              // 28 floats scratch

    const int B = in_sizes[0] / 8;

    vqc_coeffs_kernel<<<1, 64, 0, stream>>>(qw, coeffs);
    const int blocks = (B + 255) / 256;
    vqc_eval_kernel<<<blocks, 256, 0, stream>>>(inputs, coeffs, out, B);
}

// Round 2
// 75.863 us; speedup vs baseline: 2.0749x; 2.0749x over previous
//
#include <hip/hip_runtime.h>

// Kernel 1: wave-parallel precompute of the 27 trilinear coefficients.
// lane = i*8 + j holds U[i][j] (row i, column j) as one complex in 2 VGPRs.
// Gates on qubit q pair rows differing in bit m=4>>q -> lane xor (m*8).
__global__ __launch_bounds__(64) void vqc_coeffs_kernel(
    const float* __restrict__ w, float* __restrict__ Bout) {
    const int lane = threadIdx.x;   // 0..63
    const int i = lane >> 3;        // row (amplitude index)
    // column j = lane & 7

    float vr = (i == (lane & 7)) ? 1.f : 0.f;  // U = I
    float vi = 0.f;

#pragma unroll
    for (int l = 0; l < 3; ++l) {
#pragma unroll
        for (int q = 0; q < 3; ++q) {
            const int m = 4 >> q;     // row-bit for qubit q
            const int d = m << 3;     // lane xor distance
            // RY(w[l][q][0]): new0 = c*a0 - s*a1; new1 = s*a0 + c*a1
            {
                float th = 0.5f * w[(l * 3 + q) * 2 + 0];
                float s, c;
                __sincosf(th, &s, &c);
                float pr = __shfl_xor(vr, d, 64);
                float pi = __shfl_xor(vi, d, 64);
                float t = (i & m) ? s : -s;
                vr = c * vr + t * pr;
                vi = c * vi + t * pi;
            }
            // RZ(w[l][q][1]): multiply by e^{-+i t/2} = (cz, +-sz)
            {
                float ph = 0.5f * w[(l * 3 + q) * 2 + 1];
                float sz, cz;
                __sincosf(ph, &sz, &cz);
                float ei = (i & m) ? sz : -sz;
                float nr = cz * vr - ei * vi;
                float ni = cz * vi + ei * vr;
                vr = nr; vi = ni;
            }
        }
        // CNOT01: rows 4<->6, 5<->7  (i&4 -> flip row bit1 -> lane xor 16)
        {
            float pr = __shfl_xor(vr, 16, 64);
            float pi = __shfl_xor(vi, 16, 64);
            if (i & 4) { vr = pr; vi = pi; }
        }
        // CNOT12: rows 2<->3, 6<->7  (i&2 -> flip row bit0 -> lane xor 8)
        {
            float pr = __shfl_xor(vr, 8, 64);
            float pi = __shfl_xor(vi, 8, 64);
            if (i & 2) { vr = pr; vi = pi; }
        }
    }

    __shared__ float LUr[64], LUi[64], LM[64];
    LUr[lane] = vr; LUi[lane] = vi;
    __syncthreads();

    // lane = j*8 + k computes M[j][k] = sum_i sign_i * Re(conj(U[i][j])*U[i][k])
    {
        const int jj = lane >> 3, kk = lane & 7;
        float acc = 0.f;
#pragma unroll
        for (int ii = 0; ii < 8; ++ii) {
            float t = LUr[ii * 8 + jj] * LUr[ii * 8 + kk] +
                      LUi[ii * 8 + jj] * LUi[ii * 8 + kk];
            acc += (ii < 4) ? t : -t;
        }
        LM[lane] = acc;
    }
    __syncthreads();

    if (lane == 0) {
        float M[8][8];
#pragma unroll
        for (int a = 0; a < 8; ++a)
#pragma unroll
            for (int b = 0; b < 8; ++b) M[a][b] = LM[a * 8 + b];

        // Contract qubit-0: c^2=(1+cos)/2, s^2=(1-cos)/2, cs=sin/2
        float T1[3][4][4];
#pragma unroll
        for (int jl = 0; jl < 4; ++jl)
#pragma unroll
            for (int kl = 0; kl < 4; ++kl) {
                T1[0][jl][kl] = 0.5f * (M[jl][kl] + M[4 + jl][4 + kl]);
                T1[1][jl][kl] = 0.5f * (M[jl][kl] - M[4 + jl][4 + kl]);
                T1[2][jl][kl] = 0.5f * (M[jl][4 + kl] + M[4 + jl][kl]);
            }
        // Contract qubit-1
        float T2[3][3][2][2];
#pragma unroll
        for (int a = 0; a < 3; ++a)
#pragma unroll
            for (int c = 0; c < 2; ++c)
#pragma unroll
                for (int cp = 0; cp < 2; ++cp) {
                    T2[a][0][c][cp] = 0.5f * (T1[a][c][cp] + T1[a][2 + c][2 + cp]);
                    T2[a][1][c][cp] = 0.5f * (T1[a][c][cp] - T1[a][2 + c][2 + cp]);
                    T2[a][2][c][cp] = 0.5f * (T1[a][c][2 + cp] + T1[a][2 + c][cp]);
                }
        // Contract qubit-2 -> 27 coefficients
#pragma unroll
        for (int a = 0; a < 3; ++a)
#pragma unroll
            for (int b = 0; b < 3; ++b) {
                Bout[(a * 3 + b) * 3 + 0] = 0.5f * (T2[a][b][0][0] + T2[a][b][1][1]);
                Bout[(a * 3 + b) * 3 + 1] = 0.5f * (T2[a][b][0][0] - T2[a][b][1][1]);
                Bout[(a * 3 + b) * 3 + 2] = 0.5f * (T2[a][b][0][1] + T2[a][b][1][0]);
            }
        Bout[27] = 0.f;  // pad for float4 staging in kernel 2
    }
}

// Kernel 2: per-sample evaluation (unchanged; verified correct).
__global__ __launch_bounds__(256) void vqc_eval_kernel(
    const float* __restrict__ in, const float* __restrict__ coeffs,
    float* __restrict__ out, int B) {
    __shared__ float Bs[28];
    const int t = threadIdx.x;
    if (t < 7) reinterpret_cast<float4*>(Bs)[t] =
        reinterpret_cast<const float4*>(coeffs)[t];
    __syncthreads();

    const int b = blockIdx.x * 256 + t;
    if (b >= B) return;

    const float4 v = reinterpret_cast<const float4*>(in)[2 * b];
    float s0, c0, s1, c1, s2, c2;
    __sincosf(v.x, &s0, &c0);
    __sincosf(v.y, &s1, &c1);
    __sincosf(v.z, &s2, &c2);

    float e0 = 0.f, e1 = 0.f, e2 = 0.f;
#pragma unroll
    for (int a = 0; a < 3; ++a) {
        float h0 = Bs[(a * 3 + 0) * 3 + 0] + Bs[(a * 3 + 0) * 3 + 1] * c2 + Bs[(a * 3 + 0) * 3 + 2] * s2;
        float h1 = Bs[(a * 3 + 1) * 3 + 0] + Bs[(a * 3 + 1) * 3 + 1] * c2 + Bs[(a * 3 + 1) * 3 + 2] * s2;
        float h2 = Bs[(a * 3 + 2) * 3 + 0] + Bs[(a * 3 + 2) * 3 + 1] * c2 + Bs[(a * 3 + 2) * 3 + 2] * s2;
        float ea = h0 + h1 * c1 + h2 * s1;
        if (a == 0) e0 = ea; else if (a == 1) e1 = ea; else e2 = ea;
    }
    out[b] = e0 + e1 * c0 + e2 * s0;
}

extern "C" void kernel_launch(void* const* d_in, const int* in_sizes, int n_in,
                              void* d_out, int out_size, void* d_ws, size_t ws_size,
                              hipStream_t stream) {
    const float* inputs = (const float*)d_in[0];     // (B, 8) float32
    const float* qw     = (const float*)d_in[1];     // (3, 3, 2) float32
    float* out          = (float*)d_out;             // (B, 1) float32
    float* coeffs       = (float*)d_ws;              // 28 floats scratch

    const int B = in_sizes[0] / 8;

    vqc_coeffs_kernel<<<1, 64, 0, stream>>>(qw, coeffs);
    const int blocks = (B + 255) / 256;
    vqc_eval_kernel<<<blocks, 256, 0, stream>>>(inputs, coeffs, out, B);
}